// Round 5
// baseline (271.167 us; speedup 1.0000x reference)
//
#include <hip/hip_runtime.h>
#include <hip/hip_fp16.h>

#define R_TOTAL 2097152
#define M_DEPTH 8
#define C_CH 16

// One texel entry in the dup-packed layout: 64 bytes =
//   [ch0..15 @ x] (fp16, 32B) | [ch0..15 @ min(x+1,W-1)] (fp16, 32B)
struct C32 { float4 q[4]; };

// ---------------------------------------------------------------------------
// Repack [M, C, H, W] f32 -> [M, H, W, 2, C] fp16 with x-neighbor duplication.
// Source reads are nontemporal: the f32 source is never re-read this call,
// and we want L3 to retain the packed textures instead.
// ---------------------------------------------------------------------------
__global__ __launch_bounds__(256) void repack_dup_fp16(const float* __restrict__ src,
                                                       __half* __restrict__ dst,
                                                       int lgW) {
    int t = blockIdx.x * blockDim.x + threadIdx.x;   // index over M*H*W
    int W  = 1 << lgW;
    int HW = 1 << (2 * lgW);
    int m  = t >> (2 * lgW);
    int p  = t & (HW - 1);                           // y*W + x
    int x  = p & (W - 1);
    int x1off = (x == W - 1) ? 0 : 1;

    const float* s = src + (size_t)m * C_CH * HW + p;
    union { __half h[2 * C_CH]; float4 f[4]; } u;
#pragma unroll
    for (int c = 0; c < C_CH; ++c) {
        float a = __builtin_nontemporal_load(s + (size_t)c * HW);
        float b = __builtin_nontemporal_load(s + (size_t)c * HW + x1off);
        u.h[c]        = __float2half(a);
        u.h[C_CH + c] = __float2half(b);
    }
    float4* d4 = (float4*)(dst + (size_t)t * 2 * C_CH);
#pragma unroll
    for (int r = 0; r < 4; ++r) d4[r] = u.f[r];     // normal stores: keep in L2/L3
}

// ---------------------------------------------------------------------------
// Sampler on dup-packed fp16 textures. One thread per sample, 4 line loads.
// Output stores + coordinate loads are nontemporal (streaming, no reuse).
// ---------------------------------------------------------------------------
__device__ inline void corner_accum(const C32& c, float w, float wx,
                                    float acc[C_CH]) {
    const __half2* pa = (const __half2*)&c.q[0];   // ch @ x0
    const __half2* pb = (const __half2*)&c.q[2];   // ch @ x1
#pragma unroll
    for (int k = 0; k < 8; ++k) {
        float2 fa = __half22float2(pa[k]);
        float2 fb = __half22float2(pb[k]);
        acc[2 * k + 0] += w * (fa.x + wx * (fb.x - fa.x));
        acc[2 * k + 1] += w * (fa.y + wx * (fb.y - fa.y));
    }
}

__global__ __launch_bounds__(256) void sample_dup_fp16(
    const float* __restrict__ uv, const int* __restrict__ idcs,
    const float* __restrict__ sid, const __half* __restrict__ tex0p,
    const __half* __restrict__ tex1p, float* __restrict__ out) {
    int i = blockIdx.x * blockDim.x + threadIdx.x;

    float tu  = __builtin_nontemporal_load(uv + 2 * (size_t)i + 0);
    float tv  = __builtin_nontemporal_load(uv + 2 * (size_t)i + 1);
    float z   = __builtin_nontemporal_load(sid + i);
    int which = __builtin_nontemporal_load(idcs + i);

    const __half* tex = (which == 0) ? tex0p : tex1p;
    int   Wm1 = (which == 0) ? 511 : 255;
    int   W   = Wm1 + 1;
    float fw  = (float)Wm1;

    float x = fminf(fmaxf((tu + 1.0f) * 0.5f * fw, 0.0f), fw);
    float y = fminf(fmaxf((tv + 1.0f) * 0.5f * fw, 0.0f), fw);
    float d = fminf(fmaxf((z + 1.0f) * 0.5f * 7.0f, 0.0f), 7.0f);

    int x0 = (int)x, y0 = (int)y, d0 = (int)d;
    int y1 = min(y0 + 1, Wm1), d1 = min(d0 + 1, 7);
    float wx = x - (float)x0, wy = y - (float)y0, wd = d - (float)d0;

    float w_d[2] = {1.0f - wd, wd};
    float w_y[2] = {1.0f - wy, wy};
    int   ds[2]  = {d0, d1};
    int   ys[2]  = {y0, y1};

    // Issue all 4 corner-line loads (16 x dwordx4, 4 distinct 64B lines).
    // These stay cached (L2/L3) — no nt hint here.
    C32 cv[2][2];
#pragma unroll
    for (int a = 0; a < 2; ++a)
#pragma unroll
        for (int b = 0; b < 2; ++b) {
            const C32* e = (const C32*)(tex +
                ((size_t)(ds[a] * W + ys[b]) * W + x0) * (2 * C_CH));
            cv[a][b] = *e;
        }

    float acc[C_CH];
#pragma unroll
    for (int c = 0; c < C_CH; ++c) acc[c] = 0.0f;
#pragma unroll
    for (int a = 0; a < 2; ++a)
#pragma unroll
        for (int b = 0; b < 2; ++b)
            corner_accum(cv[a][b], w_d[a] * w_y[b], wx, acc);

#pragma unroll
    for (int c = 0; c < C_CH; ++c)
        __builtin_nontemporal_store(acc[c], out + (size_t)c * R_TOTAL + i);
}

// ---------------------------------------------------------------------------
// Secondary path: f32 channel-last pack, 8 lines/sample.
// ---------------------------------------------------------------------------
__global__ __launch_bounds__(256) void repack_f32(const float* __restrict__ src,
                                                  float* __restrict__ dst,
                                                  int lgHW) {
    int t = blockIdx.x * blockDim.x + threadIdx.x;
    int HW = 1 << lgHW;
    int m  = t >> lgHW;
    int p  = t & (HW - 1);
    const float* s = src + (size_t)m * C_CH * HW + p;
    float v[C_CH];
#pragma unroll
    for (int c = 0; c < C_CH; ++c) v[c] = s[(size_t)c * HW];
    float4* d4 = (float4*)(dst + (size_t)t * C_CH);
#pragma unroll
    for (int r = 0; r < 4; ++r)
        d4[r] = make_float4(v[4 * r + 0], v[4 * r + 1], v[4 * r + 2], v[4 * r + 3]);
}

__global__ __launch_bounds__(256) void sample_packed_f32(
    const float2* __restrict__ uv, const int* __restrict__ idcs,
    const float* __restrict__ sid, const float* __restrict__ tex0p,
    const float* __restrict__ tex1p, float* __restrict__ out) {
    int i = blockIdx.x * blockDim.x + threadIdx.x;

    float2 t  = uv[i];
    float  z  = sid[i];
    int which = idcs[i];

    const float* tex = (which == 0) ? tex0p : tex1p;
    int   Wm1 = (which == 0) ? 511 : 255;
    int   W   = Wm1 + 1;
    float fw  = (float)Wm1;

    float x = fminf(fmaxf((t.x + 1.0f) * 0.5f * fw, 0.0f), fw);
    float y = fminf(fmaxf((t.y + 1.0f) * 0.5f * fw, 0.0f), fw);
    float d = fminf(fmaxf((z + 1.0f) * 0.5f * 7.0f, 0.0f), 7.0f);

    int x0 = (int)x, y0 = (int)y, d0 = (int)d;
    int x1 = min(x0 + 1, Wm1), y1 = min(y0 + 1, Wm1), d1 = min(d0 + 1, 7);
    float wx = x - (float)x0, wy = y - (float)y0, wd = d - (float)d0;

    float acc[C_CH];
#pragma unroll
    for (int c = 0; c < C_CH; ++c) acc[c] = 0.0f;

    float w_d[2] = {1.0f - wd, wd};
    float w_y[2] = {1.0f - wy, wy};
    int   ds[2]  = {d0, d1};
    int   ys[2]  = {y0, y1};

#pragma unroll
    for (int a = 0; a < 2; ++a)
#pragma unroll
        for (int b = 0; b < 2; ++b) {
            float w = w_d[a] * w_y[b];
            const float* base = tex + (size_t)(ds[a] * W + ys[b]) * W * C_CH;
            const float4* pa = (const float4*)(base + (size_t)x0 * C_CH);
            const float4* pb = (const float4*)(base + (size_t)x1 * C_CH);
#pragma unroll
            for (int r = 0; r < 4; ++r) {
                float4 va = pa[r];
                float4 vb = pb[r];
                acc[4 * r + 0] += w * (va.x + wx * (vb.x - va.x));
                acc[4 * r + 1] += w * (va.y + wx * (vb.y - va.y));
                acc[4 * r + 2] += w * (va.z + wx * (vb.z - va.z));
                acc[4 * r + 3] += w * (va.w + wx * (vb.w - va.w));
            }
        }

#pragma unroll
    for (int c = 0; c < C_CH; ++c)
        out[(size_t)c * R_TOTAL + i] = acc[c];
}

// ---------------------------------------------------------------------------
// Tertiary fallback: sample directly from [M, C, H, W] f32.
// ---------------------------------------------------------------------------
__global__ __launch_bounds__(256) void sample_direct(
    const float2* __restrict__ uv, const int* __restrict__ idcs,
    const float* __restrict__ sid, const float* __restrict__ tex0,
    const float* __restrict__ tex1, float* __restrict__ out) {
    int i = blockIdx.x * blockDim.x + threadIdx.x;

    float2 t  = uv[i];
    float  z  = sid[i];
    int which = idcs[i];

    const float* tex = (which == 0) ? tex0 : tex1;
    int   Wm1 = (which == 0) ? 511 : 255;
    int   W   = Wm1 + 1;
    float fw  = (float)Wm1;

    float x = fminf(fmaxf((t.x + 1.0f) * 0.5f * fw, 0.0f), fw);
    float y = fminf(fmaxf((t.y + 1.0f) * 0.5f * fw, 0.0f), fw);
    float d = fminf(fmaxf((z + 1.0f) * 0.5f * 7.0f, 0.0f), 7.0f);

    int x0 = (int)x, y0 = (int)y, d0 = (int)d;
    int x1 = min(x0 + 1, Wm1), y1 = min(y0 + 1, Wm1), d1 = min(d0 + 1, 7);
    float wx = x - (float)x0, wy = y - (float)y0, wd = d - (float)d0;

    float w_d[2] = {1.0f - wd, wd};
    float w_y[2] = {1.0f - wy, wy};
    int   ds[2]  = {d0, d1};
    int   ys[2]  = {y0, y1};

#pragma unroll
    for (int c = 0; c < C_CH; ++c) {
        float res = 0.0f;
#pragma unroll
        for (int a = 0; a < 2; ++a)
#pragma unroll
            for (int b = 0; b < 2; ++b) {
                float w = w_d[a] * w_y[b];
                const float* base =
                    tex + ((size_t)ds[a] * C_CH + c) * W * W + (size_t)ys[b] * W;
                float va = base[x0];
                float vb = base[x1];
                res += w * (va + wx * (vb - va));
            }
        out[(size_t)c * R_TOTAL + i] = res;
    }
}

extern "C" void kernel_launch(void* const* d_in, const int* in_sizes, int n_in,
                              void* d_out, int out_size, void* d_ws, size_t ws_size,
                              hipStream_t stream) {
    const float* uv   = (const float*)d_in[0];
    const int*   idcs = (const int*)d_in[1];
    const float* sid  = (const float*)d_in[2];
    const float* tex0 = (const float*)d_in[3];
    const float* tex1 = (const float*)d_in[4];
    float*       out  = (float*)d_out;

    const size_t e0 = (size_t)M_DEPTH * 512 * 512;   // entries in tex0
    const size_t e1 = (size_t)M_DEPTH * 256 * 256;   // entries in tex1
    const size_t need_dup = (e0 + e1) * 2 * C_CH * sizeof(__half);  // ~160 MiB
    const size_t need_f32 = (e0 + e1) * C_CH * sizeof(float);       // ~160 MiB

    if (ws_size >= need_dup) {
        __half* p0 = (__half*)d_ws;
        __half* p1 = p0 + e0 * 2 * C_CH;
        repack_dup_fp16<<<(int)(e0 / 256), 256, 0, stream>>>(tex0, p0, 9);
        repack_dup_fp16<<<(int)(e1 / 256), 256, 0, stream>>>(tex1, p1, 8);
        sample_dup_fp16<<<R_TOTAL / 256, 256, 0, stream>>>(uv, idcs, sid, p0, p1, out);
    } else if (ws_size >= need_f32) {
        float* p0 = (float*)d_ws;
        float* p1 = p0 + e0 * C_CH;
        repack_f32<<<(int)(e0 / 256), 256, 0, stream>>>(tex0, p0, 18);
        repack_f32<<<(int)(e1 / 256), 256, 0, stream>>>(tex1, p1, 16);
        sample_packed_f32<<<R_TOTAL / 256, 256, 0, stream>>>((const float2*)uv, idcs, sid,
                                                             p0, p1, out);
    } else {
        sample_direct<<<R_TOTAL / 256, 256, 0, stream>>>((const float2*)uv, idcs, sid,
                                                         tex0, tex1, out);
    }
}

// Round 6
// 264.624 us; speedup vs baseline: 1.0247x; 1.0247x over previous
//
#include <hip/hip_runtime.h>
#include <hip/hip_fp16.h>

#define R_TOTAL 2097152
#define M_DEPTH 8
#define C_CH 16

// One texel entry in the dup-packed layout: 64 bytes =
//   [ch0..15 @ x] (fp16, 32B) | [ch0..15 @ min(x+1,W-1)] (fp16, 32B)
struct C32 { float4 q[4]; };

// ---------------------------------------------------------------------------
// Repack [M, C, H, W] f32 -> [M, H, W, 2, C] fp16 with x-neighbor duplication.
// Source reads nontemporal (never re-read; keep L3 for the packed textures).
// x+1 neighbor comes from lane+1 via __shfl_down (W is a multiple of 64, so
// x % 64 == lane): halves the source load count. Lane 63 reloads from memory
// unless it's the row end (border clamp -> own value).
// ---------------------------------------------------------------------------
__global__ __launch_bounds__(256) void repack_dup_fp16(const float* __restrict__ src,
                                                       __half* __restrict__ dst,
                                                       int lgW) {
    int t = blockIdx.x * blockDim.x + threadIdx.x;   // index over M*H*W
    int W  = 1 << lgW;
    int HW = 1 << (2 * lgW);
    int m  = t >> (2 * lgW);
    int p  = t & (HW - 1);                           // y*W + x
    int x  = p & (W - 1);
    int lane = threadIdx.x & 63;
    bool rowend = (x == W - 1);                      // border clamp: x+1 == x
    bool edge   = (lane == 63) && !rowend;           // neighbor lives in next wave

    const float* s = src + (size_t)m * C_CH * HW + p;

    float a[C_CH], b[C_CH];
#pragma unroll
    for (int c = 0; c < C_CH; ++c)
        a[c] = __builtin_nontemporal_load(s + (size_t)c * HW);
    // Uniform shuffle (no divergence), then patch the two special cases.
#pragma unroll
    for (int c = 0; c < C_CH; ++c) {
        float sh = __shfl_down(a[c], 1, 64);
        b[c] = rowend ? a[c] : sh;
    }
    if (edge) {
#pragma unroll
        for (int c = 0; c < C_CH; ++c)
            b[c] = __builtin_nontemporal_load(s + (size_t)c * HW + 1);
    }

    union { __half h[2 * C_CH]; float4 f[4]; } u;
#pragma unroll
    for (int c = 0; c < C_CH; ++c) {
        u.h[c]        = __float2half(a[c]);
        u.h[C_CH + c] = __float2half(b[c]);
    }
    float4* d4 = (float4*)(dst + (size_t)t * 2 * C_CH);
#pragma unroll
    for (int r = 0; r < 4; ++r) d4[r] = u.f[r];     // normal stores: keep in L2/L3
}

// ---------------------------------------------------------------------------
// Sampler on dup-packed fp16 textures. One thread per sample, 4 line loads.
// Output stores + coordinate loads are nontemporal (streaming, no reuse).
// ---------------------------------------------------------------------------
__device__ inline void corner_accum(const C32& c, float w, float wx,
                                    float acc[C_CH]) {
    const __half2* pa = (const __half2*)&c.q[0];   // ch @ x0
    const __half2* pb = (const __half2*)&c.q[2];   // ch @ x1
#pragma unroll
    for (int k = 0; k < 8; ++k) {
        float2 fa = __half22float2(pa[k]);
        float2 fb = __half22float2(pb[k]);
        acc[2 * k + 0] += w * (fa.x + wx * (fb.x - fa.x));
        acc[2 * k + 1] += w * (fa.y + wx * (fb.y - fa.y));
    }
}

__global__ __launch_bounds__(256) void sample_dup_fp16(
    const float* __restrict__ uv, const int* __restrict__ idcs,
    const float* __restrict__ sid, const __half* __restrict__ tex0p,
    const __half* __restrict__ tex1p, float* __restrict__ out) {
    int i = blockIdx.x * blockDim.x + threadIdx.x;

    float tu  = __builtin_nontemporal_load(uv + 2 * (size_t)i + 0);
    float tv  = __builtin_nontemporal_load(uv + 2 * (size_t)i + 1);
    float z   = __builtin_nontemporal_load(sid + i);
    int which = __builtin_nontemporal_load(idcs + i);

    const __half* tex = (which == 0) ? tex0p : tex1p;
    int   Wm1 = (which == 0) ? 511 : 255;
    int   W   = Wm1 + 1;
    float fw  = (float)Wm1;

    float x = fminf(fmaxf((tu + 1.0f) * 0.5f * fw, 0.0f), fw);
    float y = fminf(fmaxf((tv + 1.0f) * 0.5f * fw, 0.0f), fw);
    float d = fminf(fmaxf((z + 1.0f) * 0.5f * 7.0f, 0.0f), 7.0f);

    int x0 = (int)x, y0 = (int)y, d0 = (int)d;
    int y1 = min(y0 + 1, Wm1), d1 = min(d0 + 1, 7);
    float wx = x - (float)x0, wy = y - (float)y0, wd = d - (float)d0;

    float w_d[2] = {1.0f - wd, wd};
    float w_y[2] = {1.0f - wy, wy};
    int   ds[2]  = {d0, d1};
    int   ys[2]  = {y0, y1};

    // Issue all 4 corner-line loads (16 x dwordx4, 4 distinct 64B lines).
    // These stay cached (L2/L3) — no nt hint here.
    C32 cv[2][2];
#pragma unroll
    for (int a = 0; a < 2; ++a)
#pragma unroll
        for (int b = 0; b < 2; ++b) {
            const C32* e = (const C32*)(tex +
                ((size_t)(ds[a] * W + ys[b]) * W + x0) * (2 * C_CH));
            cv[a][b] = *e;
        }

    float acc[C_CH];
#pragma unroll
    for (int c = 0; c < C_CH; ++c) acc[c] = 0.0f;
#pragma unroll
    for (int a = 0; a < 2; ++a)
#pragma unroll
        for (int b = 0; b < 2; ++b)
            corner_accum(cv[a][b], w_d[a] * w_y[b], wx, acc);

#pragma unroll
    for (int c = 0; c < C_CH; ++c)
        __builtin_nontemporal_store(acc[c], out + (size_t)c * R_TOTAL + i);
}

// ---------------------------------------------------------------------------
// Secondary path: f32 channel-last pack, 8 lines/sample.
// ---------------------------------------------------------------------------
__global__ __launch_bounds__(256) void repack_f32(const float* __restrict__ src,
                                                  float* __restrict__ dst,
                                                  int lgHW) {
    int t = blockIdx.x * blockDim.x + threadIdx.x;
    int HW = 1 << lgHW;
    int m  = t >> lgHW;
    int p  = t & (HW - 1);
    const float* s = src + (size_t)m * C_CH * HW + p;
    float v[C_CH];
#pragma unroll
    for (int c = 0; c < C_CH; ++c) v[c] = s[(size_t)c * HW];
    float4* d4 = (float4*)(dst + (size_t)t * C_CH);
#pragma unroll
    for (int r = 0; r < 4; ++r)
        d4[r] = make_float4(v[4 * r + 0], v[4 * r + 1], v[4 * r + 2], v[4 * r + 3]);
}

__global__ __launch_bounds__(256) void sample_packed_f32(
    const float2* __restrict__ uv, const int* __restrict__ idcs,
    const float* __restrict__ sid, const float* __restrict__ tex0p,
    const float* __restrict__ tex1p, float* __restrict__ out) {
    int i = blockIdx.x * blockDim.x + threadIdx.x;

    float2 t  = uv[i];
    float  z  = sid[i];
    int which = idcs[i];

    const float* tex = (which == 0) ? tex0p : tex1p;
    int   Wm1 = (which == 0) ? 511 : 255;
    int   W   = Wm1 + 1;
    float fw  = (float)Wm1;

    float x = fminf(fmaxf((t.x + 1.0f) * 0.5f * fw, 0.0f), fw);
    float y = fminf(fmaxf((t.y + 1.0f) * 0.5f * fw, 0.0f), fw);
    float d = fminf(fmaxf((z + 1.0f) * 0.5f * 7.0f, 0.0f), 7.0f);

    int x0 = (int)x, y0 = (int)y, d0 = (int)d;
    int x1 = min(x0 + 1, Wm1), y1 = min(y0 + 1, Wm1), d1 = min(d0 + 1, 7);
    float wx = x - (float)x0, wy = y - (float)y0, wd = d - (float)d0;

    float acc[C_CH];
#pragma unroll
    for (int c = 0; c < C_CH; ++c) acc[c] = 0.0f;

    float w_d[2] = {1.0f - wd, wd};
    float w_y[2] = {1.0f - wy, wy};
    int   ds[2]  = {d0, d1};
    int   ys[2]  = {y0, y1};

#pragma unroll
    for (int a = 0; a < 2; ++a)
#pragma unroll
        for (int b = 0; b < 2; ++b) {
            float w = w_d[a] * w_y[b];
            const float* base = tex + (size_t)(ds[a] * W + ys[b]) * W * C_CH;
            const float4* pa = (const float4*)(base + (size_t)x0 * C_CH);
            const float4* pb = (const float4*)(base + (size_t)x1 * C_CH);
#pragma unroll
            for (int r = 0; r < 4; ++r) {
                float4 va = pa[r];
                float4 vb = pb[r];
                acc[4 * r + 0] += w * (va.x + wx * (vb.x - va.x));
                acc[4 * r + 1] += w * (va.y + wx * (vb.y - va.y));
                acc[4 * r + 2] += w * (va.z + wx * (vb.z - va.z));
                acc[4 * r + 3] += w * (va.w + wx * (vb.w - va.w));
            }
        }

#pragma unroll
    for (int c = 0; c < C_CH; ++c)
        out[(size_t)c * R_TOTAL + i] = acc[c];
}

// ---------------------------------------------------------------------------
// Tertiary fallback: sample directly from [M, C, H, W] f32.
// ---------------------------------------------------------------------------
__global__ __launch_bounds__(256) void sample_direct(
    const float2* __restrict__ uv, const int* __restrict__ idcs,
    const float* __restrict__ sid, const float* __restrict__ tex0,
    const float* __restrict__ tex1, float* __restrict__ out) {
    int i = blockIdx.x * blockDim.x + threadIdx.x;

    float2 t  = uv[i];
    float  z  = sid[i];
    int which = idcs[i];

    const float* tex = (which == 0) ? tex0 : tex1;
    int   Wm1 = (which == 0) ? 511 : 255;
    int   W   = Wm1 + 1;
    float fw  = (float)Wm1;

    float x = fminf(fmaxf((t.x + 1.0f) * 0.5f * fw, 0.0f), fw);
    float y = fminf(fmaxf((t.y + 1.0f) * 0.5f * fw, 0.0f), fw);
    float d = fminf(fmaxf((z + 1.0f) * 0.5f * 7.0f, 0.0f), 7.0f);

    int x0 = (int)x, y0 = (int)y, d0 = (int)d;
    int x1 = min(x0 + 1, Wm1), y1 = min(y0 + 1, Wm1), d1 = min(d0 + 1, 7);
    float wx = x - (float)x0, wy = y - (float)y0, wd = d - (float)d0;

    float w_d[2] = {1.0f - wd, wd};
    float w_y[2] = {1.0f - wy, wy};
    int   ds[2]  = {d0, d1};
    int   ys[2]  = {y0, y1};

#pragma unroll
    for (int c = 0; c < C_CH; ++c) {
        float res = 0.0f;
#pragma unroll
        for (int a = 0; a < 2; ++a)
#pragma unroll
            for (int b = 0; b < 2; ++b) {
                float w = w_d[a] * w_y[b];
                const float* base =
                    tex + ((size_t)ds[a] * C_CH + c) * W * W + (size_t)ys[b] * W;
                float va = base[x0];
                float vb = base[x1];
                res += w * (va + wx * (vb - va));
            }
        out[(size_t)c * R_TOTAL + i] = res;
    }
}

extern "C" void kernel_launch(void* const* d_in, const int* in_sizes, int n_in,
                              void* d_out, int out_size, void* d_ws, size_t ws_size,
                              hipStream_t stream) {
    const float* uv   = (const float*)d_in[0];
    const int*   idcs = (const int*)d_in[1];
    const float* sid  = (const float*)d_in[2];
    const float* tex0 = (const float*)d_in[3];
    const float* tex1 = (const float*)d_in[4];
    float*       out  = (float*)d_out;

    const size_t e0 = (size_t)M_DEPTH * 512 * 512;   // entries in tex0
    const size_t e1 = (size_t)M_DEPTH * 256 * 256;   // entries in tex1
    const size_t need_dup = (e0 + e1) * 2 * C_CH * sizeof(__half);  // ~160 MiB
    const size_t need_f32 = (e0 + e1) * C_CH * sizeof(float);       // ~160 MiB

    if (ws_size >= need_dup) {
        __half* p0 = (__half*)d_ws;
        __half* p1 = p0 + e0 * 2 * C_CH;
        repack_dup_fp16<<<(int)(e0 / 256), 256, 0, stream>>>(tex0, p0, 9);
        repack_dup_fp16<<<(int)(e1 / 256), 256, 0, stream>>>(tex1, p1, 8);
        sample_dup_fp16<<<R_TOTAL / 256, 256, 0, stream>>>(uv, idcs, sid, p0, p1, out);
    } else if (ws_size >= need_f32) {
        float* p0 = (float*)d_ws;
        float* p1 = p0 + e0 * C_CH;
        repack_f32<<<(int)(e0 / 256), 256, 0, stream>>>(tex0, p0, 18);
        repack_f32<<<(int)(e1 / 256), 256, 0, stream>>>(tex1, p1, 16);
        sample_packed_f32<<<R_TOTAL / 256, 256, 0, stream>>>((const float2*)uv, idcs, sid,
                                                             p0, p1, out);
    } else {
        sample_direct<<<R_TOTAL / 256, 256, 0, stream>>>((const float2*)uv, idcs, sid,
                                                         tex0, tex1, out);
    }
}

// Round 7
// 233.334 us; speedup vs baseline: 1.1621x; 1.1341x over previous
//
#include <hip/hip_runtime.h>
#include <hip/hip_fp16.h>

#define R_TOTAL 2097152
#define M_DEPTH 8
#define C_CH 16

typedef float f32x4 __attribute__((ext_vector_type(4)));

// One texel entry in the dup-packed layout: 64 bytes =
//   [ch0..15 @ x] (fp16, 32B) | [ch0..15 @ min(x+1,W-1)] (fp16, 32B)
struct C32 { float4 q[4]; };

// ---------------------------------------------------------------------------
// Fused repack of both textures: [M, C, H, W] f32 -> [M, H, W, 2, C] fp16
// with x-neighbor duplication.
//  - 4 consecutive entries per thread, f32x4 nontemporal source reads
//  - x+1 neighbor from in-register shift; seam element via __shfl_down
//    (rows are wave-aligned: W/4 is a multiple of 64)
//  - output staged in padded LDS (stride 17 float4), then written back with
//    fully coalesced lane-consecutive float4 stores (4 lanes per 64B line)
// ---------------------------------------------------------------------------
#define NG0 (M_DEPTH * 512 * 512 / 4)   // 524288 thread-groups for tex0
#define NG1 (M_DEPTH * 256 * 256 / 4)   // 131072 thread-groups for tex1

__global__ __launch_bounds__(256) void repack_dup_fp16_v2(
    const float* __restrict__ src0, __half* __restrict__ dst0,
    const float* __restrict__ src1, __half* __restrict__ dst1) {
    __shared__ float4 ls[4 * 17 * 64];               // 4 waves x 17408 B

    int t = blockIdx.x * 256 + threadIdx.x;
    const float* src;
    __half* dst;
    int lgW, tg;
    if (t < NG0) { src = src0; dst = dst0; lgW = 9; tg = t; }
    else         { src = src1; dst = dst1; lgW = 8; tg = t - NG0; }

    int W  = 1 << lgW;
    int HW = 1 << (2 * lgW);
    int g  = tg << 2;                                // first entry = m*HW + p
    int m  = g >> (2 * lgW);
    int p  = g & (HW - 1);                           // y*W + x, x multiple of 4
    int x  = p & (W - 1);
    int lane = threadIdx.x & 63;
    int wv   = threadIdx.x >> 6;

    const float* s = src + (size_t)m * C_CH * HW + p;

    f32x4 a[C_CH];
#pragma unroll
    for (int c = 0; c < C_CH; ++c)
        a[c] = __builtin_nontemporal_load((const f32x4*)(s + (size_t)c * HW));

    // Neighbor of x+3 is next thread's a[c].x (x+4). Rows are wave-aligned,
    // so only lane 63 needs a real load; row end clamps to a[c].w.
    bool rowend4 = (x == W - 4);
    float nb[C_CH];
#pragma unroll
    for (int c = 0; c < C_CH; ++c) nb[c] = __shfl_down(a[c].x, 1, 64);
    if (lane == 63 && !rowend4) {
#pragma unroll
        for (int c = 0; c < C_CH; ++c)
            nb[c] = __builtin_nontemporal_load(s + (size_t)c * HW + 4);
    }
    if (rowend4) {
#pragma unroll
        for (int c = 0; c < C_CH; ++c) nb[c] = a[c].w;
    }

    // Build 4 entries (16 float4 chunks) into padded LDS.
    float4* lsw = ls + wv * (17 * 64);
#pragma unroll
    for (int k = 0; k < 4; ++k) {
        union { __half h[2 * C_CH]; float4 f[4]; } u;
#pragma unroll
        for (int c = 0; c < C_CH; ++c) {
            u.h[c]        = __float2half(a[c][k]);
            u.h[C_CH + c] = __float2half(k < 3 ? a[c][k + 1] : nb[c]);
        }
#pragma unroll
        for (int r = 0; r < 4; ++r)
            lsw[lane * 17 + (k * 4 + r)] = u.f[r];
    }
    __syncthreads();

    // Coalesced writeback: wave covers 1024 consecutive float4 of dst.
    int tg_w = tg - lane;                            // wave's first group
    float4* dst4 = (float4*)dst + (size_t)tg_w * 16;
#pragma unroll
    for (int r2 = 0; r2 < 16; ++r2) {
        int j = r2 * 64 + lane;                      // global chunk in wave
        float4 v = lsw[j + (j >> 4)];                // inverse of pad-17 layout
        dst4[j] = v;
    }
}

// ---------------------------------------------------------------------------
// Sampler on dup-packed fp16 textures. One thread per sample, 4 line loads.
// Output stores + coordinate loads are nontemporal (streaming, no reuse).
// ---------------------------------------------------------------------------
__device__ inline void corner_accum(const C32& c, float w, float wx,
                                    float acc[C_CH]) {
    const __half2* pa = (const __half2*)&c.q[0];   // ch @ x0
    const __half2* pb = (const __half2*)&c.q[2];   // ch @ x1
#pragma unroll
    for (int k = 0; k < 8; ++k) {
        float2 fa = __half22float2(pa[k]);
        float2 fb = __half22float2(pb[k]);
        acc[2 * k + 0] += w * (fa.x + wx * (fb.x - fa.x));
        acc[2 * k + 1] += w * (fa.y + wx * (fb.y - fa.y));
    }
}

__global__ __launch_bounds__(256) void sample_dup_fp16(
    const float* __restrict__ uv, const int* __restrict__ idcs,
    const float* __restrict__ sid, const __half* __restrict__ tex0p,
    const __half* __restrict__ tex1p, float* __restrict__ out) {
    int i = blockIdx.x * blockDim.x + threadIdx.x;

    float tu  = __builtin_nontemporal_load(uv + 2 * (size_t)i + 0);
    float tv  = __builtin_nontemporal_load(uv + 2 * (size_t)i + 1);
    float z   = __builtin_nontemporal_load(sid + i);
    int which = __builtin_nontemporal_load(idcs + i);

    const __half* tex = (which == 0) ? tex0p : tex1p;
    int   Wm1 = (which == 0) ? 511 : 255;
    int   W   = Wm1 + 1;
    float fw  = (float)Wm1;

    float x = fminf(fmaxf((tu + 1.0f) * 0.5f * fw, 0.0f), fw);
    float y = fminf(fmaxf((tv + 1.0f) * 0.5f * fw, 0.0f), fw);
    float d = fminf(fmaxf((z + 1.0f) * 0.5f * 7.0f, 0.0f), 7.0f);

    int x0 = (int)x, y0 = (int)y, d0 = (int)d;
    int y1 = min(y0 + 1, Wm1), d1 = min(d0 + 1, 7);
    float wx = x - (float)x0, wy = y - (float)y0, wd = d - (float)d0;

    float w_d[2] = {1.0f - wd, wd};
    float w_y[2] = {1.0f - wy, wy};
    int   ds[2]  = {d0, d1};
    int   ys[2]  = {y0, y1};

    // Issue all 4 corner-line loads (16 x dwordx4, 4 distinct 64B lines).
    C32 cv[2][2];
#pragma unroll
    for (int a = 0; a < 2; ++a)
#pragma unroll
        for (int b = 0; b < 2; ++b) {
            const C32* e = (const C32*)(tex +
                ((size_t)(ds[a] * W + ys[b]) * W + x0) * (2 * C_CH));
            cv[a][b] = *e;
        }

    float acc[C_CH];
#pragma unroll
    for (int c = 0; c < C_CH; ++c) acc[c] = 0.0f;
#pragma unroll
    for (int a = 0; a < 2; ++a)
#pragma unroll
        for (int b = 0; b < 2; ++b)
            corner_accum(cv[a][b], w_d[a] * w_y[b], wx, acc);

#pragma unroll
    for (int c = 0; c < C_CH; ++c)
        __builtin_nontemporal_store(acc[c], out + (size_t)c * R_TOTAL + i);
}

// ---------------------------------------------------------------------------
// Fallback: sample directly from [M, C, H, W] f32 (workspace too small).
// ---------------------------------------------------------------------------
__global__ __launch_bounds__(256) void sample_direct(
    const float2* __restrict__ uv, const int* __restrict__ idcs,
    const float* __restrict__ sid, const float* __restrict__ tex0,
    const float* __restrict__ tex1, float* __restrict__ out) {
    int i = blockIdx.x * blockDim.x + threadIdx.x;

    float2 t  = uv[i];
    float  z  = sid[i];
    int which = idcs[i];

    const float* tex = (which == 0) ? tex0 : tex1;
    int   Wm1 = (which == 0) ? 511 : 255;
    int   W   = Wm1 + 1;
    float fw  = (float)Wm1;

    float x = fminf(fmaxf((t.x + 1.0f) * 0.5f * fw, 0.0f), fw);
    float y = fminf(fmaxf((t.y + 1.0f) * 0.5f * fw, 0.0f), fw);
    float d = fminf(fmaxf((z + 1.0f) * 0.5f * 7.0f, 0.0f), 7.0f);

    int x0 = (int)x, y0 = (int)y, d0 = (int)d;
    int x1 = min(x0 + 1, Wm1), y1 = min(y0 + 1, Wm1), d1 = min(d0 + 1, 7);
    float wx = x - (float)x0, wy = y - (float)y0, wd = d - (float)d0;

    float w_d[2] = {1.0f - wd, wd};
    float w_y[2] = {1.0f - wy, wy};
    int   ds[2]  = {d0, d1};
    int   ys[2]  = {y0, y1};

#pragma unroll
    for (int c = 0; c < C_CH; ++c) {
        float res = 0.0f;
#pragma unroll
        for (int a = 0; a < 2; ++a)
#pragma unroll
            for (int b = 0; b < 2; ++b) {
                float w = w_d[a] * w_y[b];
                const float* base =
                    tex + ((size_t)ds[a] * C_CH + c) * W * W + (size_t)ys[b] * W;
                float va = base[x0];
                float vb = base[x1];
                res += w * (va + wx * (vb - va));
            }
        out[(size_t)c * R_TOTAL + i] = res;
    }
}

extern "C" void kernel_launch(void* const* d_in, const int* in_sizes, int n_in,
                              void* d_out, int out_size, void* d_ws, size_t ws_size,
                              hipStream_t stream) {
    const float* uv   = (const float*)d_in[0];
    const int*   idcs = (const int*)d_in[1];
    const float* sid  = (const float*)d_in[2];
    const float* tex0 = (const float*)d_in[3];
    const float* tex1 = (const float*)d_in[4];
    float*       out  = (float*)d_out;

    const size_t e0 = (size_t)M_DEPTH * 512 * 512;   // entries in tex0
    const size_t e1 = (size_t)M_DEPTH * 256 * 256;   // entries in tex1
    const size_t need_dup = (e0 + e1) * 2 * C_CH * sizeof(__half);  // ~160 MiB

    if (ws_size >= need_dup) {
        __half* p0 = (__half*)d_ws;
        __half* p1 = p0 + e0 * 2 * C_CH;
        repack_dup_fp16_v2<<<(NG0 + NG1) / 256, 256, 0, stream>>>(tex0, p0, tex1, p1);
        sample_dup_fp16<<<R_TOTAL / 256, 256, 0, stream>>>(uv, idcs, sid, p0, p1, out);
    } else {
        sample_direct<<<R_TOTAL / 256, 256, 0, stream>>>((const float2*)uv, idcs, sid,
                                                         tex0, tex1, out);
    }
}